// Round 8
// baseline (232.860 us; speedup 1.0000x reference)
//
#include <hip/hip_runtime.h>
#include <hip/hip_bf16.h>
#include <math.h>

#define N_NODES 50000
#define N_EDGES 600000
#define D_IN 256
#define D_GNN 128
#define SCAN_BLOCKS ((N_NODES + 255) / 256)    // 196
#define GEMM_BLOCKS ((N_NODES + 63) / 64)      // 782
#define DEG_BLOCKS ((N_EDGES + 511) / 512)     // 1172

typedef short s16x8 __attribute__((ext_vector_type(8)));
typedef float f32x4 __attribute__((ext_vector_type(4)));

__device__ __forceinline__ unsigned short f2bf(float f) {
  unsigned int u = __float_as_uint(f);
  u += 0x7FFFu + ((u >> 16) & 1u);  // RNE
  return (unsigned short)(u >> 16);
}

// pack 8 f32 -> 8 bf16 (RNE) via v_cvt_pk_bf16_f32
__device__ __forceinline__ s16x8 cvt8(float4 a0, float4 a1) {
  union { s16x8 v; __hip_bfloat162 h[4]; } u;
  u.h[0] = __float22bfloat162_rn(make_float2(a0.x, a0.y));
  u.h[1] = __float22bfloat162_rn(make_float2(a0.z, a0.w));
  u.h[2] = __float22bfloat162_rn(make_float2(a1.x, a1.y));
  u.h[3] = __float22bfloat162_rn(make_float2(a1.z, a1.w));
  return u.v;
}

// ---------------------------------------------------------------------------
// Prologue: zero deg[] + pack Wc = [W_l|W_r] into B-fragment order (bf16):
// Wcp[((ks*256 + col)*4 + q)*8 + j] = [Wl|Wr][ks*32 + q*8 + j][col]
// ---------------------------------------------------------------------------
__global__ __launch_bounds__(256) void pack0(
    const float* __restrict__ Wl, const float* __restrict__ Wr,
    ushort* __restrict__ Wcp, int* __restrict__ deg) {
  int i = blockIdx.x * 256 + threadIdx.x;
  if (i < N_NODES) deg[i] = 0;
  if (i < 8192) {  // one 16B B-fragment per thread
    int q = i & 3, col = (i >> 2) & 255, ks = i >> 10;
    const float* W = (col < 128) ? Wl : Wr;
    int c = col & 127;
    int k0 = ks * 32 + q * 8;
    s16x8 v;
#pragma unroll
    for (int j = 0; j < 8; j++) v[j] = (short)f2bf(W[(k0 + j) * D_GNN + c]);
    *((s16x8*)(Wcp + (size_t)i * 8)) = v;
  }
}

// ---------------------------------------------------------------------------
// Fused GEMM + degree count. Blocks [0, GEMM_BLOCKS): MFMA GEMM
// [y_l|y_r] = x @ [W_l|W_r], block = 64 rows x 256 cols, 8 waves
// (2 row groups x 4 col groups), wave = 32x64 (2x4 16x16x32 tiles).
// A frags loaded from f32 x with in-register cvt; the 4x col-group
// redundancy is served by L1/L2 (same CU / same XCD). No LDS, no barrier.
// Blocks [GEMM_BLOCKS, +DEG_BLOCKS): 600K scattered int atomics (deg count)
// — latency-bound, overlaps with the MFMA blocks' compute.
// ---------------------------------------------------------------------------
__global__ __launch_bounds__(512) void gemm_deg(
    const float* __restrict__ x, const ushort* __restrict__ Wcp,
    const float* __restrict__ b_l, ushort* __restrict__ yb,
    ushort* __restrict__ yrb, const int* __restrict__ ei,
    int* __restrict__ deg) {
  if (blockIdx.x >= GEMM_BLOCKS) {  // degree-count section
    int i = (blockIdx.x - GEMM_BLOCKS) * 512 + threadIdx.x;
    if (i < N_EDGES) atomicAdd(&deg[ei[N_EDGES + i]], 1);
    return;
  }

  const int t = threadIdx.x;
  const int l = t & 63;
  const int w = t >> 6;        // 8 waves
  const int wrow = w & 1;      // 2 row groups of 32
  const int wcol = w >> 1;     // 4 col groups of 64
  const int rowBase = blockIdx.x * 64 + wrow * 32;
  const int lq = l >> 4, l16 = l & 15;

  f32x4 acc[2][4];
#pragma unroll
  for (int a = 0; a < 2; a++)
#pragma unroll
    for (int b = 0; b < 4; b++) acc[a][b] = (f32x4){0.f, 0.f, 0.f, 0.f};

  const float* aptr[2];
#pragma unroll
  for (int nt = 0; nt < 2; nt++) {
    int r = rowBase + nt * 16 + l16;
    if (r >= N_NODES) r = N_NODES - 1;  // clamp; stores guarded
    aptr[nt] = x + (size_t)r * 256 + lq * 8;
  }
  const ushort* bptr[4];
#pragma unroll
  for (int ct = 0; ct < 4; ct++) {
    int col = wcol * 64 + ct * 16 + l16;
    bptr[ct] = Wcp + ((size_t)col * 4 + lq) * 8;
  }

  s16x8 A[2], B[4], An[2], Bn[4];
#pragma unroll
  for (int nt = 0; nt < 2; nt++)
    A[nt] = cvt8(((const float4*)aptr[nt])[0], ((const float4*)aptr[nt])[1]);
#pragma unroll
  for (int ct = 0; ct < 4; ct++) B[ct] = *((const s16x8*)(bptr[ct]));

#pragma unroll
  for (int ks = 0; ks < 8; ks++) {
    if (ks < 7) {  // prefetch + convert next K-step while MFMAs run
#pragma unroll
      for (int nt = 0; nt < 2; nt++) {
        const float4* p = (const float4*)(aptr[nt] + (ks + 1) * 32);
        An[nt] = cvt8(p[0], p[1]);
      }
#pragma unroll
      for (int ct = 0; ct < 4; ct++)
        Bn[ct] = *((const s16x8*)(bptr[ct] + (size_t)(ks + 1) * 256 * 32));
    }
#pragma unroll
    for (int nt = 0; nt < 2; nt++)
#pragma unroll
      for (int ct = 0; ct < 4; ct++)
        acc[nt][ct] = __builtin_amdgcn_mfma_f32_16x16x32_bf16(
            A[nt], B[ct], acc[nt][ct], 0, 0, 0);
#pragma unroll
    for (int nt = 0; nt < 2; nt++) A[nt] = An[nt];
#pragma unroll
    for (int ct = 0; ct < 4; ct++) B[ct] = Bn[ct];
  }

  // C/D layout: col = lane&15, row = (lane>>4)*4 + reg  [m89/m91-verified]
#pragma unroll
  for (int nt = 0; nt < 2; nt++) {
#pragma unroll
    for (int ct = 0; ct < 4; ct++) {
      int gcol = wcol * 64 + ct * 16 + l16;  // 0..255
#pragma unroll
      for (int r = 0; r < 4; r++) {
        int node = rowBase + nt * 16 + lq * 4 + r;
        if (node < N_NODES) {
          if (gcol < 128)
            yb[(size_t)node * D_GNN + gcol] = f2bf(acc[nt][ct][r]);
          else
            yrb[(size_t)node * D_GNN + (gcol - 128)] =
                f2bf(acc[nt][ct][r] + b_l[gcol - 128]);
        }
      }
    }
  }
}

// ---------------------------------------------------------------------------
// Stage 1: per-block exclusive scan of deg (256/block), emit block sums.
// ---------------------------------------------------------------------------
__global__ __launch_bounds__(256) void partial_scan(
    const int* __restrict__ deg, int* __restrict__ rowptr,
    int* __restrict__ blockSums) {
  __shared__ int s[256];
  const int t = threadIdx.x;
  const int n = blockIdx.x * 256 + t;
  int d = (n < N_NODES) ? deg[n] : 0;
  s[t] = d;
  __syncthreads();
#pragma unroll
  for (int off = 1; off < 256; off <<= 1) {
    int v = (t >= off) ? s[t - off] : 0;
    __syncthreads();
    s[t] += v;
    __syncthreads();
  }
  if (n < N_NODES) rowptr[n] = s[t] - d;  // exclusive local prefix
  if (t == 255) blockSums[blockIdx.x] = s[255];
}

// ---------------------------------------------------------------------------
// Stage 2+3 fused: every block scans the 196 block sums in LDS, picks its
// own exclusive offset, adds it to rowptr.
// ---------------------------------------------------------------------------
__global__ __launch_bounds__(256) void add_off(int* __restrict__ rowptr,
                                               const int* __restrict__ bsums) {
  __shared__ int s[256];
  const int t = threadIdx.x;
  int d = (t < SCAN_BLOCKS) ? bsums[t] : 0;
  s[t] = d;
  __syncthreads();
#pragma unroll
  for (int off = 1; off < 256; off <<= 1) {
    int v = (t >= off) ? s[t - off] : 0;
    __syncthreads();
    s[t] += v;
    __syncthreads();
  }
  const int boff = (blockIdx.x == 0) ? 0 : s[blockIdx.x - 1];
  const int n = blockIdx.x * 256 + t;
  if (n < N_NODES) rowptr[n] += boff;
}

// ---------------------------------------------------------------------------
// Destructive slot fill: atomicAdd on rowptr itself returns the slot. After
// this kernel rowptr[n] == row END; gather compensates.
// ---------------------------------------------------------------------------
__global__ __launch_bounds__(256) void fill_kernel(const int* __restrict__ ei,
                                                   int* __restrict__ rowptr,
                                                   int* __restrict__ col) {
  int e = blockIdx.x * 256 + threadIdx.x;
  if (e >= N_EDGES) return;
  int dst = ei[N_EDGES + e];
  int pos = atomicAdd(&rowptr[dst], 1);
  col[pos] = ei[e];  // src
}

// ---------------------------------------------------------------------------
// Gather + epilogue + pred head. One wave per node; lane owns dims
// {2*lane, 2*lane+1}. rowptr is post-fill (shifted): end = rowptr[node],
// begin = node ? rowptr[node-1] : 0.
// ---------------------------------------------------------------------------
__global__ __launch_bounds__(256) void gather_pred(
    const int* __restrict__ rowptr, const int* __restrict__ col,
    const ushort* __restrict__ yb, const ushort* __restrict__ yrb,
    const float* __restrict__ Wfc, const float* __restrict__ bfc,
    float* __restrict__ h, float* __restrict__ pred) {
  const int node = (blockIdx.x * 256 + threadIdx.x) >> 6;
  const int lane = threadIdx.x & 63;
  if (node >= N_NODES) return;
  const int b = node ? rowptr[node - 1] : 0;
  const int e = rowptr[node];
  float ax = 0.f, ay = 0.f;
  const unsigned int* y32 = (const unsigned int*)yb;
  for (int i = b; i < e; i += 64) {
    int c = (i + lane < e) ? col[i + lane] : 0;
    int m = min(64, e - i);
    int j = 0;
    for (; j + 4 <= m; j += 4) {
      int s0 = __shfl(c, j), s1 = __shfl(c, j + 1);
      int s2 = __shfl(c, j + 2), s3 = __shfl(c, j + 3);
      unsigned int v0 = y32[(size_t)s0 * 64 + lane];
      unsigned int v1 = y32[(size_t)s1 * 64 + lane];
      unsigned int v2 = y32[(size_t)s2 * 64 + lane];
      unsigned int v3 = y32[(size_t)s3 * 64 + lane];
      ax += __uint_as_float(v0 << 16) + __uint_as_float(v1 << 16) +
            __uint_as_float(v2 << 16) + __uint_as_float(v3 << 16);
      ay += __uint_as_float(v0 & 0xFFFF0000u) + __uint_as_float(v1 & 0xFFFF0000u) +
            __uint_as_float(v2 & 0xFFFF0000u) + __uint_as_float(v3 & 0xFFFF0000u);
    }
    for (; j < m; j++) {
      int s0 = __shfl(c, j);
      unsigned int v0 = y32[(size_t)s0 * 64 + lane];
      ax += __uint_as_float(v0 << 16);
      ay += __uint_as_float(v0 & 0xFFFF0000u);
    }
  }
  const int deg = e - b;
  const float ic = deg > 0 ? 1.f / (float)deg : 0.f;
  unsigned int yrv = ((const unsigned int*)yrb)[(size_t)node * 64 + lane];
  float h0 = ax * ic + __uint_as_float(yrv << 16);
  float h1 = ay * ic + __uint_as_float(yrv & 0xFFFF0000u);
  float2 hv; hv.x = h0; hv.y = h1;
  ((float2*)h)[(size_t)node * 64 + lane] = hv;
  float s = h0 * Wfc[2 * lane] + h1 * Wfc[2 * lane + 1];
#pragma unroll
  for (int off = 32; off > 0; off >>= 1) s += __shfl_down(s, off);
  if (lane == 0) pred[node] = 1.f / (1.f + expf(-(s + bfc[0])));
}

extern "C" void kernel_launch(void* const* d_in, const int* in_sizes, int n_in,
                              void* d_out, int out_size, void* d_ws,
                              size_t ws_size, hipStream_t stream) {
  const float* x   = (const float*)d_in[0];
  const int*   ei  = (const int*)d_in[1];
  const float* Wl  = (const float*)d_in[2];
  const float* bl  = (const float*)d_in[3];
  const float* Wr  = (const float*)d_in[4];
  const float* Wfc = (const float*)d_in[5];
  const float* bfc = (const float*)d_in[6];

  float* out  = (float*)d_out;
  float* h    = out;                        // [N,128] final h (f32)
  float* pred = out + (size_t)N_NODES * D_GNN;

  ushort* Wcp  = (ushort*)d_ws;                               // 8192*8 bf16
  ushort* yb   = Wcp + 8192 * 8;                              // [N,128] bf16
  ushort* yrb  = yb + (size_t)N_NODES * D_GNN;                // [N,128] bf16
  int* rowptr  = (int*)(yrb + (size_t)N_NODES * D_GNN);       // [N]
  int* tmp     = rowptr + N_NODES;                            // [N] deg
  int* col     = tmp + N_NODES;                               // [E]
  int* bsums   = col + N_EDGES;                               // [256]

  // --- prologue: zero deg + pack W (bf16 B-fragment order) ---
  pack0<<<SCAN_BLOCKS, 256, 0, stream>>>(Wl, Wr, Wcp, tmp);

  // --- fused: MFMA GEMM (y_l, y_r+b_l) + degree count (overlapped) ---
  gemm_deg<<<GEMM_BLOCKS + DEG_BLOCKS, 512, 0, stream>>>(x, Wcp, bl, yb, yrb,
                                                         ei, tmp);

  // --- CSR: 2-stage scan -> destructive fill ---
  partial_scan<<<SCAN_BLOCKS, 256, 0, stream>>>(tmp, rowptr, bsums);
  add_off<<<SCAN_BLOCKS, 256, 0, stream>>>(rowptr, bsums);
  fill_kernel<<<(N_EDGES + 255) / 256, 256, 0, stream>>>(ei, rowptr, col);

  // --- mean gather + h epilogue + pred head ---
  gather_pred<<<(N_NODES * 64 + 255) / 256, 256, 0, stream>>>(
      rowptr, col, yb, yrb, Wfc, bfc, h, pred);
}

// Round 9
// 189.870 us; speedup vs baseline: 1.2264x; 1.2264x over previous
//
#include <hip/hip_runtime.h>
#include <hip/hip_bf16.h>
#include <math.h>

#define N_NODES 50000
#define N_EDGES 600000
#define D_IN 256
#define D_GNN 128
#define CAP 32        // padded adjacency slots per node; overflow handled exactly
#define MAX_OVER 8192
#define LDS_STRIDE 264  // 256 + 8 bf16 pad

typedef short s16x8 __attribute__((ext_vector_type(8)));
typedef float f32x4 __attribute__((ext_vector_type(4)));

__device__ __forceinline__ unsigned short f2bf(float f) {
  unsigned int u = __float_as_uint(f);
  u += 0x7FFFu + ((u >> 16) & 1u);  // RNE
  return (unsigned short)(u >> 16);
}

__device__ __forceinline__ ushort4 cvt4(float4 a) {
  union { ushort4 u4; __hip_bfloat162 h[2]; } u;
  u.h[0] = __float22bfloat162_rn(make_float2(a.x, a.y));
  u.h[1] = __float22bfloat162_rn(make_float2(a.z, a.w));
  return u.u4;
}

// ---------------------------------------------------------------------------
// Prologue: zero cursor[] + overflow count + pack Wc=[W_l|W_r] to B-fragment
// order (bf16): Wcp[((ks*256+col)*4+q)*8+j] = [Wl|Wr][ks*32+q*8+j][col]
// ---------------------------------------------------------------------------
__global__ __launch_bounds__(256) void pack0(
    const float* __restrict__ Wl, const float* __restrict__ Wr,
    ushort* __restrict__ Wcp, int* __restrict__ cursor,
    int* __restrict__ ovcnt) {
  int i = blockIdx.x * 256 + threadIdx.x;
  if (i < N_NODES) cursor[i] = 0;
  if (i == 0) ovcnt[0] = 0;
  if (i < 8192) {  // one 16B B-fragment per thread
    int q = i & 3, col = (i >> 2) & 255, ks = i >> 10;
    const float* W = (col < 128) ? Wl : Wr;
    int c = col & 127;
    int k0 = ks * 32 + q * 8;
    s16x8 v;
#pragma unroll
    for (int j = 0; j < 8; j++) v[j] = (short)f2bf(W[(k0 + j) * D_GNN + c]);
    *((s16x8*)(Wcp + (size_t)i * 8)) = v;
  }
}

// ---------------------------------------------------------------------------
// Single-pass padded adjacency fill: cursor[dst]++ gives the slot; slots
// >= CAP go to an exact overflow list (expected ~0 entries for Poisson(12)
// degrees). cursor[n] ends as the TRUE degree of n.
// ---------------------------------------------------------------------------
__global__ __launch_bounds__(256) void fill_pad(
    const int* __restrict__ ei, int* __restrict__ cursor,
    int* __restrict__ colp, int* __restrict__ ovcnt, int2* __restrict__ over) {
  int e = blockIdx.x * 256 + threadIdx.x;
  if (e >= N_EDGES) return;
  int src = ei[e];
  int dst = ei[N_EDGES + e];
  int pos = atomicAdd(&cursor[dst], 1);
  if (pos < CAP) {
    colp[dst * CAP + pos] = src;
  } else {
    int o = atomicAdd(ovcnt, 1);
    if (o < MAX_OVER) over[o] = make_int2(dst, src);
  }
}

// ---------------------------------------------------------------------------
// MFMA GEMM, single pass over x (R7-proven): [y_l|y_r] = x @ [W_l|W_r].
// Block = 64 rows x 256 cols, 512 threads = 8 waves (2 row x 4 col groups),
// wave = 32x64 (2x4 16x16x32 tiles). 64x256 f32 strip -> bf16 LDS once per
// block; B frags from L2-resident Wcp with next-K register prefetch.
// cols 0..127 -> y_l (bf16), 128..255 -> y_r + b_l (bf16).
// ---------------------------------------------------------------------------
__global__ __launch_bounds__(512) void mfma_gemm(
    const float* __restrict__ x, const ushort* __restrict__ Wcp,
    const float* __restrict__ b_l, ushort* __restrict__ yb,
    ushort* __restrict__ yrb) {
  __shared__ ushort xs[64 * LDS_STRIDE];  // 33792 B
  const int t = threadIdx.x;
  const int n0 = blockIdx.x * 64;

#pragma unroll
  for (int j = 0; j < 8; j++) {
    int idx = t + j * 512;
    int row = idx >> 6, col4 = idx & 63;
    int gn = n0 + row;
    if (gn >= N_NODES) gn = N_NODES - 1;  // clamp; stores guarded
    float4 v = ((const float4*)x)[(size_t)gn * 64 + col4];
    *((ushort4*)(xs + row * LDS_STRIDE + col4 * 4)) = cvt4(v);
  }
  __syncthreads();

  const int l = t & 63;
  const int w = t >> 6;
  const int wrow = w & 1;
  const int wcol = w >> 1;
  const int lq = l >> 4, l16 = l & 15;

  f32x4 acc[2][4];
#pragma unroll
  for (int a = 0; a < 2; a++)
#pragma unroll
    for (int b = 0; b < 4; b++) acc[a][b] = (f32x4){0.f, 0.f, 0.f, 0.f};

  const ushort* abase[2];
#pragma unroll
  for (int nt = 0; nt < 2; nt++)
    abase[nt] = xs + (wrow * 32 + nt * 16 + l16) * LDS_STRIDE + lq * 8;
  const ushort* bptr[4];
#pragma unroll
  for (int ct = 0; ct < 4; ct++) {
    int col = wcol * 64 + ct * 16 + l16;
    bptr[ct] = Wcp + ((size_t)col * 4 + lq) * 8;
  }

  s16x8 B[4], Bn[4];
#pragma unroll
  for (int ct = 0; ct < 4; ct++) B[ct] = *((const s16x8*)(bptr[ct]));

#pragma unroll
  for (int ks = 0; ks < 8; ks++) {
    s16x8 A[2];
#pragma unroll
    for (int nt = 0; nt < 2; nt++)
      A[nt] = *((const s16x8*)(abase[nt] + ks * 32));
    if (ks < 7) {
#pragma unroll
      for (int ct = 0; ct < 4; ct++)
        Bn[ct] = *((const s16x8*)(bptr[ct] + (size_t)(ks + 1) * 256 * 32));
    }
#pragma unroll
    for (int nt = 0; nt < 2; nt++)
#pragma unroll
      for (int ct = 0; ct < 4; ct++)
        acc[nt][ct] = __builtin_amdgcn_mfma_f32_16x16x32_bf16(
            A[nt], B[ct], acc[nt][ct], 0, 0, 0);
#pragma unroll
    for (int ct = 0; ct < 4; ct++) B[ct] = Bn[ct];
  }

  // C/D layout: col = lane&15, row = (lane>>4)*4 + reg  [m89/m91-verified]
#pragma unroll
  for (int nt = 0; nt < 2; nt++) {
#pragma unroll
    for (int ct = 0; ct < 4; ct++) {
      int gcol = wcol * 64 + ct * 16 + l16;  // 0..255
#pragma unroll
      for (int r = 0; r < 4; r++) {
        int node = n0 + wrow * 32 + nt * 16 + lq * 4 + r;
        if (node < N_NODES) {
          if (gcol < 128)
            yb[(size_t)node * D_GNN + gcol] = f2bf(acc[nt][ct][r]);
          else
            yrb[(size_t)node * D_GNN + (gcol - 128)] =
                f2bf(acc[nt][ct][r] + b_l[gcol - 128]);
        }
      }
    }
  }
}

// ---------------------------------------------------------------------------
// Gather (padded adjacency) + epilogue + pred head. One wave per node; lane
// owns dims {2*lane, 2*lane+1}. True degree = cursor[node]; first min(deg,
// CAP) neighbors in colp[node*CAP..], rest in the overflow list (scanned
// exactly; wave-uniform broadcast reads, expected length ~0).
// ---------------------------------------------------------------------------
__global__ __launch_bounds__(256) void gather_pred(
    const int* __restrict__ cursor, const int* __restrict__ colp,
    const int* __restrict__ ovcnt, const int2* __restrict__ over,
    const ushort* __restrict__ yb, const ushort* __restrict__ yrb,
    const float* __restrict__ Wfc, const float* __restrict__ bfc,
    float* __restrict__ h, float* __restrict__ pred) {
  const int node = (blockIdx.x * 256 + threadIdx.x) >> 6;
  const int lane = threadIdx.x & 63;
  if (node >= N_NODES) return;
  const int degt = cursor[node];
  const int m = min(degt, CAP);
  float ax = 0.f, ay = 0.f;
  const unsigned int* y32 = (const unsigned int*)yb;

  int c = (lane < m) ? colp[node * CAP + lane] : 0;
  int j = 0;
  for (; j + 4 <= m; j += 4) {
    int s0 = __shfl(c, j), s1 = __shfl(c, j + 1);
    int s2 = __shfl(c, j + 2), s3 = __shfl(c, j + 3);
    unsigned int v0 = y32[(size_t)s0 * 64 + lane];
    unsigned int v1 = y32[(size_t)s1 * 64 + lane];
    unsigned int v2 = y32[(size_t)s2 * 64 + lane];
    unsigned int v3 = y32[(size_t)s3 * 64 + lane];
    ax += __uint_as_float(v0 << 16) + __uint_as_float(v1 << 16) +
          __uint_as_float(v2 << 16) + __uint_as_float(v3 << 16);
    ay += __uint_as_float(v0 & 0xFFFF0000u) + __uint_as_float(v1 & 0xFFFF0000u) +
          __uint_as_float(v2 & 0xFFFF0000u) + __uint_as_float(v3 & 0xFFFF0000u);
  }
  for (; j < m; j++) {
    int s0 = __shfl(c, j);
    unsigned int v0 = y32[(size_t)s0 * 64 + lane];
    ax += __uint_as_float(v0 << 16);
    ay += __uint_as_float(v0 & 0xFFFF0000u);
  }
  if (degt > CAP) {  // exact overflow handling (rare; wave-uniform)
    int nov = min(ovcnt[0], MAX_OVER);
    for (int k = 0; k < nov; k++) {
      int2 ov = over[k];
      if (ov.x == node) {
        unsigned int v0 = y32[(size_t)ov.y * 64 + lane];
        ax += __uint_as_float(v0 << 16);
        ay += __uint_as_float(v0 & 0xFFFF0000u);
      }
    }
  }

  const float ic = degt > 0 ? 1.f / (float)degt : 0.f;
  unsigned int yrv = ((const unsigned int*)yrb)[(size_t)node * 64 + lane];
  float h0 = ax * ic + __uint_as_float(yrv << 16);
  float h1 = ay * ic + __uint_as_float(yrv & 0xFFFF0000u);
  float2 hv; hv.x = h0; hv.y = h1;
  ((float2*)h)[(size_t)node * 64 + lane] = hv;
  float s = h0 * Wfc[2 * lane] + h1 * Wfc[2 * lane + 1];
#pragma unroll
  for (int off = 32; off > 0; off >>= 1) s += __shfl_down(s, off);
  if (lane == 0) pred[node] = 1.f / (1.f + expf(-(s + bfc[0])));
}

extern "C" void kernel_launch(void* const* d_in, const int* in_sizes, int n_in,
                              void* d_out, int out_size, void* d_ws,
                              size_t ws_size, hipStream_t stream) {
  const float* x   = (const float*)d_in[0];
  const int*   ei  = (const int*)d_in[1];
  const float* Wl  = (const float*)d_in[2];
  const float* bl  = (const float*)d_in[3];
  const float* Wr  = (const float*)d_in[4];
  const float* Wfc = (const float*)d_in[5];
  const float* bfc = (const float*)d_in[6];

  float* out  = (float*)d_out;
  float* h    = out;                        // [N,128] final h (f32)
  float* pred = out + (size_t)N_NODES * D_GNN;

  ushort* Wcp   = (ushort*)d_ws;                              // 128 KB
  ushort* yb    = Wcp + 8192 * 8;                             // [N,128] bf16
  ushort* yrb   = yb + (size_t)N_NODES * D_GNN;               // [N,128] bf16
  int*   cursor = (int*)(yrb + (size_t)N_NODES * D_GNN);      // [N]
  int*   ovcnt  = cursor + N_NODES;                           // [1]
  int2*  over   = (int2*)(ovcnt + 1);                         // [MAX_OVER]
  int*   colp   = (int*)(over + MAX_OVER);                    // [N*CAP]

  // --- prologue: zero cursor/ovcnt + pack W ---
  pack0<<<(N_NODES + 255) / 256, 256, 0, stream>>>(Wl, Wr, Wcp, cursor, ovcnt);

  // --- padded adjacency build (single atomic pass) ---
  fill_pad<<<(N_EDGES + 255) / 256, 256, 0, stream>>>(ei, cursor, colp, ovcnt,
                                                      over);

  // --- y_l = x@W_l (bf16), y_r = x@W_r + b_l (bf16) ---
  mfma_gemm<<<(N_NODES + 63) / 64, 512, 0, stream>>>(x, Wcp, bl, yb, yrb);

  // --- mean gather + h epilogue + pred head ---
  gather_pred<<<(N_NODES * 64 + 255) / 256, 256, 0, stream>>>(
      cursor, colp, ovcnt, over, yb, yrb, Wfc, bfc, h, pred);
}